// Round 1
// baseline (931.348 us; speedup 1.0000x reference)
//
#include <hip/hip_runtime.h>
#include <math.h>

#define D 4096
#define F 384
#define NB 32
#define NG 196
#define NL 36
#define SROWS 21760
#define TROWS 12544
#define TCHUNK 6272   /* 32*196 teacher-region rows per i-chunk */
#define LCHUNK 1152   /* 32*36 student local-chunk rows */
#define NPART (SROWS + 576)

// ---------- helpers ----------
__device__ inline float get_invtemp(const int* ep_ptr) {
  int ep = *ep_ptr;
  double t = (ep < 30) ? (0.04 + (double)ep * (0.03 / 29.0)) : 0.07;
  return 1.0f / (float)t;
}

__device__ inline float warp_max(float v) {
#pragma unroll
  for (int o = 32; o; o >>= 1) v = fmaxf(v, __shfl_xor(v, o));
  return v;
}
__device__ inline float warp_sum(float v) {
#pragma unroll
  for (int o = 32; o; o >>= 1) v += __shfl_xor(v, o);
  return v;
}
// 256-thread (4-wave) block reductions; sc is 4-float LDS scratch.
__device__ inline float block_max(float v, float* sc) {
  v = warp_max(v);
  __syncthreads();
  if ((threadIdx.x & 63) == 0) sc[threadIdx.x >> 6] = v;
  __syncthreads();
  return fmaxf(fmaxf(sc[0], sc[1]), fmaxf(sc[2], sc[3]));
}
__device__ inline float block_sum(float v, float* sc) {
  v = warp_sum(v);
  __syncthreads();
  if ((threadIdx.x & 63) == 0) sc[threadIdx.x >> 6] = v;
  __syncthreads();
  return (sc[0] + sc[1]) + (sc[2] + sc[3]);
}

__device__ inline unsigned long long umax64(unsigned long long a, unsigned long long b) {
  return a > b ? a : b;
}
// monotone float->u32, then pack with inverted idx so equal keys prefer SMALLER idx (first-max, like jnp.argmax)
__device__ inline unsigned long long pack_key(float sim, int tc) {
  unsigned bts = __float_as_uint(sim);
  bts = (bts & 0x80000000u) ? ~bts : (bts | 0x80000000u);
  return ((unsigned long long)bts << 32) | (unsigned long long)(0xFFFFFFFFu - (unsigned)tc);
}
__device__ inline void unpack4(float4 v, float* dst) {
  dst[0] = v.x; dst[1] = v.y; dst[2] = v.z; dst[3] = v.w;
}

// ---------- K1: teacher feat inverse norms ----------
__global__ __launch_bounds__(256) void k_tnorm(const float* __restrict__ tfea,
                                               float* __restrict__ invtn) {
  int gw = (blockIdx.x * 256 + threadIdx.x) >> 6;  // one wave per row
  int lane = threadIdx.x & 63;
  if (gw >= TROWS) return;
  const float* p = tfea + (size_t)gw * F;
  float ss = 0.f;
#pragma unroll
  for (int k = 0; k < 6; k++) { float v = p[lane + 64 * k]; ss += v * v; }
  ss = warp_sum(ss);
  if (lane == 0) invtn[gw] = 1.0f / fmaxf(sqrtf(ss), 1e-12f);
}

// ---------- K2: cosine-sim GEMM + fused argmax ----------
// grid: 512 s-tiles * 4 t-tiles. s-tile layout per b: [4 tiles j=0][4 tiles j=1][8 tiles j=2..9]
__global__ __launch_bounds__(256) void k_sim(const float* __restrict__ sfea,
                                             const float* __restrict__ tfea,
                                             const float* __restrict__ invtn,
                                             unsigned long long* __restrict__ keys) {
  __shared__ float s_sm[64][65];
  __shared__ float t_sm0[64][65];
  __shared__ float t_sm1[64][65];
  int tid = threadIdx.x;
  int bid = blockIdx.x;
  int st = bid >> 2, tt = bid & 3;
  int b = st >> 4, w = st & 15;
  int j, tile;
  if (w < 4)      { j = 0; tile = w; }
  else if (w < 8) { j = 1; tile = w - 4; }
  else            { j = 2 + (w - 8); tile = 0; }
  int S = (j < 2) ? NG : NL;
  int off = (j < 2) ? j * TCHUNK : 2 * TCHUNK + (j - 2) * LCHUNK;
  int base_s = off + b * S + tile * 64;
  int vs = S - tile * 64; if (vs > 64) vs = 64;     // valid s rows in tile
  bool ni2 = (j >= 2);
  int i0 = (j == 0) ? 1 : 0;                        // if ni2: i0=0, second i=1
  int tc0 = tt * 64;
  int vt = NG - tc0; if (vt > 64) vt = 64;          // valid t cols (4 for tt=3)
  int trb0 = i0 * TCHUNK + b * NG + tc0;
  int trb1 = TCHUNK + b * NG + tc0;
  int tx = tid & 15, ty = tid >> 4;

  float acc0[4][4] = {{0.f}}, acc1[4][4] = {{0.f}};

  for (int kt = 0; kt < 6; kt++) {
    int k0 = kt * 64;
    __syncthreads();
#pragma unroll
    for (int rr = 0; rr < 4; rr++) {
      int idx = rr * 256 + tid;
      int row = idx >> 4, c4 = idx & 15;
      float4 v = make_float4(0.f, 0.f, 0.f, 0.f);
      if (row < vs) v = *(const float4*)(sfea + (size_t)(base_s + row) * F + k0 + c4 * 4);
      s_sm[row][c4 * 4 + 0] = v.x; s_sm[row][c4 * 4 + 1] = v.y;
      s_sm[row][c4 * 4 + 2] = v.z; s_sm[row][c4 * 4 + 3] = v.w;
    }
#pragma unroll
    for (int rr = 0; rr < 4; rr++) {
      int idx = rr * 256 + tid;
      int row = idx >> 4, c4 = idx & 15;
      float4 v = make_float4(0.f, 0.f, 0.f, 0.f);
      if (row < vt) v = *(const float4*)(tfea + (size_t)(trb0 + row) * F + k0 + c4 * 4);
      t_sm0[row][c4 * 4 + 0] = v.x; t_sm0[row][c4 * 4 + 1] = v.y;
      t_sm0[row][c4 * 4 + 2] = v.z; t_sm0[row][c4 * 4 + 3] = v.w;
    }
    if (ni2) {
#pragma unroll
      for (int rr = 0; rr < 4; rr++) {
        int idx = rr * 256 + tid;
        int row = idx >> 4, c4 = idx & 15;
        float4 v = make_float4(0.f, 0.f, 0.f, 0.f);
        if (row < vt) v = *(const float4*)(tfea + (size_t)(trb1 + row) * F + k0 + c4 * 4);
        t_sm1[row][c4 * 4 + 0] = v.x; t_sm1[row][c4 * 4 + 1] = v.y;
        t_sm1[row][c4 * 4 + 2] = v.z; t_sm1[row][c4 * 4 + 3] = v.w;
      }
    }
    __syncthreads();
#pragma unroll 8
    for (int kk = 0; kk < 64; kk++) {
      float sv[4], tv[4];
#pragma unroll
      for (int m = 0; m < 4; m++) sv[m] = s_sm[ty * 4 + m][kk];
#pragma unroll
      for (int n = 0; n < 4; n++) tv[n] = t_sm0[tx * 4 + n][kk];
#pragma unroll
      for (int m = 0; m < 4; m++)
#pragma unroll
        for (int n = 0; n < 4; n++) acc0[m][n] += sv[m] * tv[n];
      if (ni2) {
        float wv[4];
#pragma unroll
        for (int n = 0; n < 4; n++) wv[n] = t_sm1[tx * 4 + n][kk];
#pragma unroll
        for (int m = 0; m < 4; m++)
#pragma unroll
          for (int n = 0; n < 4; n++) acc1[m][n] += sv[m] * wv[n];
      }
    }
  }

  // finalize: scale by teacher inv-norm, masked argmax, reduce over tx, atomicMax
  float inv0[4], inv1[4];
#pragma unroll
  for (int n = 0; n < 4; n++) {
    int tc = tx * 4 + n;
    inv0[n] = (tc < vt) ? invtn[trb0 + tc] : 0.f;
    inv1[n] = (ni2 && tc < vt) ? invtn[trb1 + tc] : 0.f;
  }
#pragma unroll
  for (int m = 0; m < 4; m++) {
    int sl = ty * 4 + m;
    unsigned long long best0 = 0ull, best1 = 0ull;
#pragma unroll
    for (int n = 0; n < 4; n++) {
      int tcl = tx * 4 + n;
      if (tcl < vt) {
        int tc = tc0 + tcl;
        best0 = umax64(best0, pack_key(acc0[m][n] * inv0[n], tc));
        if (ni2) best1 = umax64(best1, pack_key(acc1[m][n] * inv1[n], tc));
      }
    }
#pragma unroll
    for (int o = 1; o < 16; o <<= 1) {
      best0 = umax64(best0, __shfl_xor(best0, o));
      best1 = umax64(best1, __shfl_xor(best1, o));
    }
    if (tx == 0 && sl < vs) {
      atomicMax(&keys[(size_t)i0 * SROWS + base_s + sl], best0);
      if (ni2) atomicMax(&keys[(size_t)SROWS + base_s + sl], best1);
    }
  }
}

// ---------- K3: region cross-entropy (one block per student region row) ----------
__global__ __launch_bounds__(256) void k_region(const float* __restrict__ sreg,
                                                const float* __restrict__ treg,
                                                const float* __restrict__ cgrid,
                                                const unsigned long long* __restrict__ keys,
                                                const int* __restrict__ epoch,
                                                float* __restrict__ partials) {
  __shared__ float sc[4];
  int r = blockIdx.x, tid = threadIdx.x;
  int j, rem;
  if (r < TCHUNK)          { j = 0; rem = r; }
  else if (r < 2 * TCHUNK) { j = 1; rem = r - TCHUNK; }
  else { int q = r - 2 * TCHUNK; j = 2 + q / LCHUNK; rem = q - (j - 2) * LCHUNK; }
  int S = (j < 2) ? NG : NL;
  int b = rem / S;
  float invtemp = get_invtemp(epoch);

  // student row -> regs, scaled by 1/0.1
  const float4* sp = (const float4*)(sreg + (size_t)r * D);
  float sv[16];
  unpack4(sp[tid], sv); unpack4(sp[tid + 256], sv + 4);
  unpack4(sp[tid + 512], sv + 8); unpack4(sp[tid + 768], sv + 12);
#pragma unroll
  for (int k = 0; k < 16; k++) sv[k] *= 10.f;

  float m = -INFINITY;
#pragma unroll
  for (int k = 0; k < 16; k++) m = fmaxf(m, sv[k]);
  float M = block_max(m, sc);
  float e = 0.f;
#pragma unroll
  for (int k = 0; k < 16; k++) e += expf(sv[k] - M);
  float Ssum = block_sum(e, sc);
  float base = M + logf(Ssum);

  const float4* cp = (const float4*)cgrid;
  float cv[16];
  unpack4(cp[tid], cv); unpack4(cp[tid + 256], cv + 4);
  unpack4(cp[tid + 512], cv + 8); unpack4(cp[tid + 768], cv + 12);

  int ni = (j >= 2) ? 2 : 1;
  int i0 = (j == 0) ? 1 : 0;
  float wsel = 0.5f / (float)(S * NB * 18);
  float acc = 0.f;
  for (int q = 0; q < ni; q++) {
    int i = (q == 0) ? i0 : 1;
    unsigned long long kv = keys[(size_t)i * SROWS + r];
    int ind = (int)(0xFFFFFFFFu - (unsigned)(kv & 0xFFFFFFFFull));
    const float4* tp = (const float4*)(treg + (size_t)(i * TCHUNK + b * NG + ind) * D);
    float tv[16];
    unpack4(tp[tid], tv); unpack4(tp[tid + 256], tv + 4);
    unpack4(tp[tid + 512], tv + 8); unpack4(tp[tid + 768], tv + 12);
#pragma unroll
    for (int k = 0; k < 16; k++) tv[k] = (tv[k] - cv[k]) * invtemp;
    float tm = -INFINITY;
#pragma unroll
    for (int k = 0; k < 16; k++) tm = fmaxf(tm, tv[k]);
    float Tm = block_max(tm, sc);
    float es = 0.f, ed = 0.f;
#pragma unroll
    for (int k = 0; k < 16; k++) {
      float ee = expf(tv[k] - Tm);
      es += ee; ed += ee * sv[k];
    }
    es = block_sum(es, sc);
    ed = block_sum(ed, sc);
    acc += wsel * (base - ed / es);
  }
  if (tid == 0) partials[r] = acc;
}

// ---------- K4: cls cross-entropy (one block per (pair, b)) ----------
__global__ __launch_bounds__(256) void k_cls(const float* __restrict__ scls,
                                             const float* __restrict__ tcls,
                                             const float* __restrict__ center,
                                             const int* __restrict__ epoch,
                                             float* __restrict__ part) {
  __shared__ float sc[4];
  int bid = blockIdx.x, tid = threadIdx.x;
  int p = bid >> 5, b = bid & 31;
  int i = p / 9, jj = p % 9;
  int j = (jj < i) ? jj : jj + 1;
  float invtemp = get_invtemp(epoch);

  const float4* sp = (const float4*)(scls + (size_t)(j * NB + b) * D);
  float sv[16];
  unpack4(sp[tid], sv); unpack4(sp[tid + 256], sv + 4);
  unpack4(sp[tid + 512], sv + 8); unpack4(sp[tid + 768], sv + 12);
#pragma unroll
  for (int k = 0; k < 16; k++) sv[k] *= 10.f;
  float m = -INFINITY;
#pragma unroll
  for (int k = 0; k < 16; k++) m = fmaxf(m, sv[k]);
  float M = block_max(m, sc);
  float e = 0.f;
#pragma unroll
  for (int k = 0; k < 16; k++) e += expf(sv[k] - M);
  float Ssum = block_sum(e, sc);
  float base = M + logf(Ssum);

  const float4* cp = (const float4*)center;
  const float4* tp = (const float4*)(tcls + (size_t)(i * NB + b) * D);
  float tv[16], cv[16];
  unpack4(cp[tid], cv); unpack4(cp[tid + 256], cv + 4);
  unpack4(cp[tid + 512], cv + 8); unpack4(cp[tid + 768], cv + 12);
  unpack4(tp[tid], tv); unpack4(tp[tid + 256], tv + 4);
  unpack4(tp[tid + 512], tv + 8); unpack4(tp[tid + 768], tv + 12);
#pragma unroll
  for (int k = 0; k < 16; k++) tv[k] = (tv[k] - cv[k]) * invtemp;
  float tm = -INFINITY;
#pragma unroll
  for (int k = 0; k < 16; k++) tm = fmaxf(tm, tv[k]);
  float Tm = block_max(tm, sc);
  float es = 0.f, ed = 0.f;
#pragma unroll
  for (int k = 0; k < 16; k++) {
    float ee = expf(tv[k] - Tm);
    es += ee; ed += ee * sv[k];
  }
  es = block_sum(es, sc);
  ed = block_sum(ed, sc);
  if (tid == 0) part[bid] = (base - ed / es) * (0.5f / 576.f);
}

// ---------- K5: deterministic final reduce ----------
__global__ __launch_bounds__(1024) void k_final(const float* __restrict__ partials,
                                                float* __restrict__ out, int n) {
  __shared__ float sc[16];
  int tid = threadIdx.x;
  float s = 0.f;
  for (int idx = tid; idx < n; idx += 1024) s += partials[idx];
  s = warp_sum(s);
  if ((tid & 63) == 0) sc[tid >> 6] = s;
  __syncthreads();
  if (tid < 64) {
    float v = (tid < 16) ? sc[tid] : 0.f;
    v = warp_sum(v);
    if (tid == 0) out[0] = v;
  }
}

extern "C" void kernel_launch(void* const* d_in, const int* in_sizes, int n_in,
                              void* d_out, int out_size, void* d_ws, size_t ws_size,
                              hipStream_t stream) {
  const float* s_cls = (const float*)d_in[0];
  const float* s_reg = (const float*)d_in[1];
  const float* s_fea = (const float*)d_in[2];
  const float* t_cls = (const float*)d_in[3];
  const float* t_reg = (const float*)d_in[4];
  const float* t_fea = (const float*)d_in[5];
  const float* center = (const float*)d_in[6];
  const float* cgrid = (const float*)d_in[7];
  const int* epoch = (const int*)d_in[8];

  char* ws = (char*)d_ws;
  unsigned long long* keys = (unsigned long long*)ws;       // 2*21760*8 = 348160 B
  float* invtn = (float*)(ws + 348160);                     // 12544*4  = 50176 B
  float* partials = (float*)(ws + 398336);                  // 22336*4  = 89344 B

  hipMemsetAsync(keys, 0, (size_t)2 * SROWS * sizeof(unsigned long long), stream);
  k_tnorm<<<TROWS / 4, 256, 0, stream>>>(t_fea, invtn);
  k_sim<<<2048, 256, 0, stream>>>(s_fea, t_fea, invtn, keys);
  k_region<<<SROWS, 256, 0, stream>>>(s_reg, t_reg, cgrid, keys, epoch, partials);
  k_cls<<<576, 256, 0, stream>>>(s_cls, t_cls, center, epoch, partials + SROWS);
  k_final<<<1, 1024, 0, stream>>>(partials, (float*)d_out, NPART);
}

// Round 2
// 795.638 us; speedup vs baseline: 1.1706x; 1.1706x over previous
//
#include <hip/hip_runtime.h>
#include <math.h>

#define D 4096
#define F 384
#define NB 32
#define NG 196
#define NL 36
#define SROWS 21760
#define TROWS 12544
#define TCHUNK 6272   /* 32*196 teacher-region rows per i-chunk */
#define LCHUNK 1152   /* 32*36 student local-chunk rows */
#define NPART (SROWS + 576)
#define KT 32         /* k-tile for sim GEMM */
#define PADW 68       /* padded LDS row width (words), 16B-aligned */

// ---------- helpers ----------
__device__ inline float get_invtemp(const int* ep_ptr) {
  int ep = *ep_ptr;
  double t = (ep < 30) ? (0.04 + (double)ep * (0.03 / 29.0)) : 0.07;
  return 1.0f / (float)t;
}

__device__ inline float warp_max(float v) {
#pragma unroll
  for (int o = 32; o; o >>= 1) v = fmaxf(v, __shfl_xor(v, o));
  return v;
}
__device__ inline float warp_sum(float v) {
#pragma unroll
  for (int o = 32; o; o >>= 1) v += __shfl_xor(v, o);
  return v;
}
// 256-thread (4-wave) block reductions; sc is 4-float LDS scratch.
__device__ inline float block_max(float v, float* sc) {
  v = warp_max(v);
  __syncthreads();
  if ((threadIdx.x & 63) == 0) sc[threadIdx.x >> 6] = v;
  __syncthreads();
  return fmaxf(fmaxf(sc[0], sc[1]), fmaxf(sc[2], sc[3]));
}
__device__ inline float block_sum(float v, float* sc) {
  v = warp_sum(v);
  __syncthreads();
  if ((threadIdx.x & 63) == 0) sc[threadIdx.x >> 6] = v;
  __syncthreads();
  return (sc[0] + sc[1]) + (sc[2] + sc[3]);
}

__device__ inline unsigned long long umax64(unsigned long long a, unsigned long long b) {
  return a > b ? a : b;
}
// monotone float->u32, then pack with inverted idx so equal keys prefer SMALLER idx (first-max, like jnp.argmax)
__device__ inline unsigned long long pack_key(float sim, int tc) {
  unsigned bts = __float_as_uint(sim);
  bts = (bts & 0x80000000u) ? ~bts : (bts | 0x80000000u);
  return ((unsigned long long)bts << 32) | (unsigned long long)(0xFFFFFFFFu - (unsigned)tc);
}
__device__ inline void unpack4(float4 v, float* dst) {
  dst[0] = v.x; dst[1] = v.y; dst[2] = v.z; dst[3] = v.w;
}

// student-region global row for (cat, b, tile position p)
// cat 0: j=0 rows; cat 1: j=1 rows; cat 2: packed locals p in [0,288)
__device__ inline int srow_of(int cat, int b, int p) {
  if (cat == 0) return b * NG + p;
  if (cat == 1) return TCHUNK + b * NG + p;
  int j = p / 36;           // 0..7 -> actual crop j-2
  int pos = p - j * 36;
  return 2 * TCHUNK + j * LCHUNK + b * NL + pos;
}

// ---------- K1: teacher feat inverse norms ----------
__global__ __launch_bounds__(256) void k_tnorm(const float* __restrict__ tfea,
                                               float* __restrict__ invtn) {
  int gw = (blockIdx.x * 256 + threadIdx.x) >> 6;  // one wave per row
  int lane = threadIdx.x & 63;
  if (gw >= TROWS) return;
  const float* p = tfea + (size_t)gw * F;
  float ss = 0.f;
#pragma unroll
  for (int k = 0; k < 6; k++) { float v = p[lane + 64 * k]; ss += v * v; }
  ss = warp_sum(ss);
  if (lane == 0) invtn[gw] = 1.0f / fmaxf(sqrtf(ss), 1e-12f);
}

// ---------- K2: cosine-sim GEMM + fused argmax (K-major LDS, b128 reads) ----------
// grid: 32 b * 13 s-tiles * 4 t-tiles = 1664 blocks.
// s-tiles per b: 0..3 -> j=0 (196 rows), 4..7 -> j=1 (196 rows), 8..12 -> packed locals (288 rows)
__global__ __launch_bounds__(256) void k_sim(const float* __restrict__ sfea,
                                             const float* __restrict__ tfea,
                                             const float* __restrict__ invtn,
                                             unsigned long long* __restrict__ keys) {
  __shared__ float s_km[KT][PADW];
  __shared__ float tA_km[KT][PADW];
  __shared__ float tB_km[KT][PADW];
  int tid = threadIdx.x;
  int bid = blockIdx.x;
  int tt = bid & 3;
  int rest = bid >> 2;
  int st = rest % 13;
  int b = rest / 13;
  int cat, base_p;
  if (st < 4)      { cat = 0; base_p = st * 64; }
  else if (st < 8) { cat = 1; base_p = (st - 4) * 64; }
  else             { cat = 2; base_p = (st - 8) * 64; }
  int vs = ((cat < 2) ? NG : 288) - base_p; if (vs > 64) vs = 64;
  bool ni2 = (cat == 2);
  int iA = (cat == 0) ? 1 : 0;
  int tc0 = tt * 64;
  int vt = NG - tc0; if (vt > 64) vt = 64;
  int gA = iA * TCHUNK + b * NG + tc0;   // teacher base row for accA
  int gB = TCHUNK + b * NG + tc0;        // teacher base row for accB (locals only)
  int tx = tid & 15, ty = tid >> 4;

  // fixed per-thread load slots: rows (row0, row0+32), k-group c4
  int row0 = tid >> 3, c4 = tid & 7;
  int row1 = row0 + 32;
  bool sv0 = row0 < vs, sv1 = row1 < vs;
  bool tv0 = row0 < vt, tv1 = row1 < vt;
  const float* sp0 = sfea + (size_t)srow_of(cat, b, base_p + (sv0 ? row0 : 0)) * F + c4 * 4;
  const float* sp1 = sfea + (size_t)srow_of(cat, b, base_p + (sv1 ? row1 : 0)) * F + c4 * 4;
  const float* tpA0 = tfea + (size_t)(gA + (tv0 ? row0 : 0)) * F + c4 * 4;
  const float* tpA1 = tfea + (size_t)(gA + (tv1 ? row1 : 0)) * F + c4 * 4;
  const float* tpB0 = tfea + (size_t)(gB + (tv0 ? row0 : 0)) * F + c4 * 4;
  const float* tpB1 = tfea + (size_t)(gB + (tv1 ? row1 : 0)) * F + c4 * 4;
  int kbase = c4 * 4;

  float accA[4][4] = {{0.f}}, accB[4][4] = {{0.f}};
  const float4 z4 = make_float4(0.f, 0.f, 0.f, 0.f);

  for (int kt = 0; kt < F / KT; kt++) {
    int k0 = kt * KT;
    float4 a0 = sv0 ? *(const float4*)(sp0 + k0) : z4;
    float4 a1 = sv1 ? *(const float4*)(sp1 + k0) : z4;
    float4 b0 = tv0 ? *(const float4*)(tpA0 + k0) : z4;
    float4 b1 = tv1 ? *(const float4*)(tpA1 + k0) : z4;
    float4 c0 = z4, c1 = z4;
    if (ni2) {
      c0 = tv0 ? *(const float4*)(tpB0 + k0) : z4;
      c1 = tv1 ? *(const float4*)(tpB1 + k0) : z4;
    }
    __syncthreads();
    s_km[kbase + 0][row0] = a0.x; s_km[kbase + 1][row0] = a0.y;
    s_km[kbase + 2][row0] = a0.z; s_km[kbase + 3][row0] = a0.w;
    s_km[kbase + 0][row1] = a1.x; s_km[kbase + 1][row1] = a1.y;
    s_km[kbase + 2][row1] = a1.z; s_km[kbase + 3][row1] = a1.w;
    tA_km[kbase + 0][row0] = b0.x; tA_km[kbase + 1][row0] = b0.y;
    tA_km[kbase + 2][row0] = b0.z; tA_km[kbase + 3][row0] = b0.w;
    tA_km[kbase + 0][row1] = b1.x; tA_km[kbase + 1][row1] = b1.y;
    tA_km[kbase + 2][row1] = b1.z; tA_km[kbase + 3][row1] = b1.w;
    if (ni2) {
      tB_km[kbase + 0][row0] = c0.x; tB_km[kbase + 1][row0] = c0.y;
      tB_km[kbase + 2][row0] = c0.z; tB_km[kbase + 3][row0] = c0.w;
      tB_km[kbase + 0][row1] = c1.x; tB_km[kbase + 1][row1] = c1.y;
      tB_km[kbase + 2][row1] = c1.z; tB_km[kbase + 3][row1] = c1.w;
    }
    __syncthreads();
    if (ni2) {
#pragma unroll 8
      for (int kk = 0; kk < KT; kk++) {
        float4 s4 = *(const float4*)&s_km[kk][ty * 4];
        float4 t4 = *(const float4*)&tA_km[kk][tx * 4];
        float4 u4 = *(const float4*)&tB_km[kk][tx * 4];
        float sv[4], tv[4], uv[4];
        unpack4(s4, sv); unpack4(t4, tv); unpack4(u4, uv);
#pragma unroll
        for (int m = 0; m < 4; m++)
#pragma unroll
          for (int n = 0; n < 4; n++) {
            accA[m][n] += sv[m] * tv[n];
            accB[m][n] += sv[m] * uv[n];
          }
      }
    } else {
#pragma unroll 8
      for (int kk = 0; kk < KT; kk++) {
        float4 s4 = *(const float4*)&s_km[kk][ty * 4];
        float4 t4 = *(const float4*)&tA_km[kk][tx * 4];
        float sv[4], tv[4];
        unpack4(s4, sv); unpack4(t4, tv);
#pragma unroll
        for (int m = 0; m < 4; m++)
#pragma unroll
          for (int n = 0; n < 4; n++) accA[m][n] += sv[m] * tv[n];
      }
    }
  }

  // finalize: scale by teacher inv-norm, masked argmax, reduce over tx, atomicMax
  float invA[4], invB[4];
#pragma unroll
  for (int n = 0; n < 4; n++) {
    int tcl = tx * 4 + n;
    invA[n] = (tcl < vt) ? invtn[gA + tcl] : 0.f;
    invB[n] = (ni2 && tcl < vt) ? invtn[gB + tcl] : 0.f;
  }
#pragma unroll
  for (int m = 0; m < 4; m++) {
    int sl = ty * 4 + m;
    unsigned long long bestA = 0ull, bestB = 0ull;
#pragma unroll
    for (int n = 0; n < 4; n++) {
      int tcl = tx * 4 + n;
      if (tcl < vt) {
        int tc = tc0 + tcl;
        bestA = umax64(bestA, pack_key(accA[m][n] * invA[n], tc));
        if (ni2) bestB = umax64(bestB, pack_key(accB[m][n] * invB[n], tc));
      }
    }
#pragma unroll
    for (int o = 1; o < 16; o <<= 1) {
      bestA = umax64(bestA, __shfl_xor(bestA, o));
      bestB = umax64(bestB, __shfl_xor(bestB, o));
    }
    if (tx == 0 && sl < vs) {
      int sr = srow_of(cat, b, base_p + sl);
      atomicMax(&keys[(size_t)iA * SROWS + sr], bestA);
      if (ni2) atomicMax(&keys[(size_t)SROWS + sr], bestB);
    }
  }
}

// ---------- K3: region cross-entropy (one block per student region row) ----------
__global__ __launch_bounds__(256) void k_region(const float* __restrict__ sreg,
                                                const float* __restrict__ treg,
                                                const float* __restrict__ cgrid,
                                                const unsigned long long* __restrict__ keys,
                                                const int* __restrict__ epoch,
                                                float* __restrict__ partials) {
  __shared__ float sc[4];
  int r = blockIdx.x, tid = threadIdx.x;
  int j, rem;
  if (r < TCHUNK)          { j = 0; rem = r; }
  else if (r < 2 * TCHUNK) { j = 1; rem = r - TCHUNK; }
  else { int q = r - 2 * TCHUNK; j = 2 + q / LCHUNK; rem = q - (j - 2) * LCHUNK; }
  int S = (j < 2) ? NG : NL;
  int b = rem / S;
  float invtemp = get_invtemp(epoch);

  // student row -> regs, scaled by 1/0.1
  const float4* sp = (const float4*)(sreg + (size_t)r * D);
  float sv[16];
  unpack4(sp[tid], sv); unpack4(sp[tid + 256], sv + 4);
  unpack4(sp[tid + 512], sv + 8); unpack4(sp[tid + 768], sv + 12);
#pragma unroll
  for (int k = 0; k < 16; k++) sv[k] *= 10.f;

  float m = -INFINITY;
#pragma unroll
  for (int k = 0; k < 16; k++) m = fmaxf(m, sv[k]);
  float M = block_max(m, sc);
  float e = 0.f;
#pragma unroll
  for (int k = 0; k < 16; k++) e += expf(sv[k] - M);
  float Ssum = block_sum(e, sc);
  float base = M + logf(Ssum);

  const float4* cp = (const float4*)cgrid;
  float cv[16];
  unpack4(cp[tid], cv); unpack4(cp[tid + 256], cv + 4);
  unpack4(cp[tid + 512], cv + 8); unpack4(cp[tid + 768], cv + 12);

  int ni = (j >= 2) ? 2 : 1;
  int i0 = (j == 0) ? 1 : 0;
  float wsel = 0.5f / (float)(S * NB * 18);
  float acc = 0.f;
  for (int q = 0; q < ni; q++) {
    int i = (q == 0) ? i0 : 1;
    unsigned long long kv = keys[(size_t)i * SROWS + r];
    int ind = (int)(0xFFFFFFFFu - (unsigned)(kv & 0xFFFFFFFFull));
    const float4* tp = (const float4*)(treg + (size_t)(i * TCHUNK + b * NG + ind) * D);
    float tv[16];
    unpack4(tp[tid], tv); unpack4(tp[tid + 256], tv + 4);
    unpack4(tp[tid + 512], tv + 8); unpack4(tp[tid + 768], tv + 12);
#pragma unroll
    for (int k = 0; k < 16; k++) tv[k] = (tv[k] - cv[k]) * invtemp;
    float tm = -INFINITY;
#pragma unroll
    for (int k = 0; k < 16; k++) tm = fmaxf(tm, tv[k]);
    float Tm = block_max(tm, sc);
    float es = 0.f, ed = 0.f;
#pragma unroll
    for (int k = 0; k < 16; k++) {
      float ee = expf(tv[k] - Tm);
      es += ee; ed += ee * sv[k];
    }
    es = block_sum(es, sc);
    ed = block_sum(ed, sc);
    acc += wsel * (base - ed / es);
  }
  if (tid == 0) partials[r] = acc;
}

// ---------- K4: cls cross-entropy (one block per (pair, b)) ----------
__global__ __launch_bounds__(256) void k_cls(const float* __restrict__ scls,
                                             const float* __restrict__ tcls,
                                             const float* __restrict__ center,
                                             const int* __restrict__ epoch,
                                             float* __restrict__ part) {
  __shared__ float sc[4];
  int bid = blockIdx.x, tid = threadIdx.x;
  int p = bid >> 5, b = bid & 31;
  int i = p / 9, jj = p % 9;
  int j = (jj < i) ? jj : jj + 1;
  float invtemp = get_invtemp(epoch);

  const float4* sp = (const float4*)(scls + (size_t)(j * NB + b) * D);
  float sv[16];
  unpack4(sp[tid], sv); unpack4(sp[tid + 256], sv + 4);
  unpack4(sp[tid + 512], sv + 8); unpack4(sp[tid + 768], sv + 12);
#pragma unroll
  for (int k = 0; k < 16; k++) sv[k] *= 10.f;
  float m = -INFINITY;
#pragma unroll
  for (int k = 0; k < 16; k++) m = fmaxf(m, sv[k]);
  float M = block_max(m, sc);
  float e = 0.f;
#pragma unroll
  for (int k = 0; k < 16; k++) e += expf(sv[k] - M);
  float Ssum = block_sum(e, sc);
  float base = M + logf(Ssum);

  const float4* cp = (const float4*)center;
  const float4* tp = (const float4*)(tcls + (size_t)(i * NB + b) * D);
  float tv[16], cv[16];
  unpack4(cp[tid], cv); unpack4(cp[tid + 256], cv + 4);
  unpack4(cp[tid + 512], cv + 8); unpack4(cp[tid + 768], cv + 12);
  unpack4(tp[tid], tv); unpack4(tp[tid + 256], tv + 4);
  unpack4(tp[tid + 512], tv + 8); unpack4(tp[tid + 768], tv + 12);
#pragma unroll
  for (int k = 0; k < 16; k++) tv[k] = (tv[k] - cv[k]) * invtemp;
  float tm = -INFINITY;
#pragma unroll
  for (int k = 0; k < 16; k++) tm = fmaxf(tm, tv[k]);
  float Tm = block_max(tm, sc);
  float es = 0.f, ed = 0.f;
#pragma unroll
  for (int k = 0; k < 16; k++) {
    float ee = expf(tv[k] - Tm);
    es += ee; ed += ee * sv[k];
  }
  es = block_sum(es, sc);
  ed = block_sum(ed, sc);
  if (tid == 0) part[bid] = (base - ed / es) * (0.5f / 576.f);
}

// ---------- K5: deterministic final reduce ----------
__global__ __launch_bounds__(1024) void k_final(const float* __restrict__ partials,
                                                float* __restrict__ out, int n) {
  __shared__ float sc[16];
  int tid = threadIdx.x;
  float s = 0.f;
  for (int idx = tid; idx < n; idx += 1024) s += partials[idx];
  s = warp_sum(s);
  if ((tid & 63) == 0) sc[tid >> 6] = s;
  __syncthreads();
  if (tid < 64) {
    float v = (tid < 16) ? sc[tid] : 0.f;
    v = warp_sum(v);
    if (tid == 0) out[0] = v;
  }
}

extern "C" void kernel_launch(void* const* d_in, const int* in_sizes, int n_in,
                              void* d_out, int out_size, void* d_ws, size_t ws_size,
                              hipStream_t stream) {
  const float* s_cls = (const float*)d_in[0];
  const float* s_reg = (const float*)d_in[1];
  const float* s_fea = (const float*)d_in[2];
  const float* t_cls = (const float*)d_in[3];
  const float* t_reg = (const float*)d_in[4];
  const float* t_fea = (const float*)d_in[5];
  const float* center = (const float*)d_in[6];
  const float* cgrid = (const float*)d_in[7];
  const int* epoch = (const int*)d_in[8];

  char* ws = (char*)d_ws;
  unsigned long long* keys = (unsigned long long*)ws;       // 2*21760*8 = 348160 B
  float* invtn = (float*)(ws + 348160);                     // 12544*4  = 50176 B
  float* partials = (float*)(ws + 398336);                  // 22336*4  = 89344 B

  hipMemsetAsync(keys, 0, (size_t)2 * SROWS * sizeof(unsigned long long), stream);
  k_tnorm<<<TROWS / 4, 256, 0, stream>>>(t_fea, invtn);
  k_sim<<<32 * 13 * 4, 256, 0, stream>>>(s_fea, t_fea, invtn, keys);
  k_region<<<SROWS, 256, 0, stream>>>(s_reg, t_reg, cgrid, keys, epoch, partials);
  k_cls<<<576, 256, 0, stream>>>(s_cls, t_cls, center, epoch, partials + SROWS);
  k_final<<<1, 1024, 0, stream>>>(partials, (float*)d_out, NPART);
}